// Round 1
// baseline (537.030 us; speedup 1.0000x reference)
//
#include <hip/hip_runtime.h>

// ChainGNN: B=64, ENC_IN=64, ENC_HID=256, N=2048, GH=128
// Exploits: (1) A_hat tridiagonal (chain) -> neighbor mix, not dense matmul
//           (2) layer-2 collapse: y = out1@Wout + A*(LN(out1)@(Wg2@Wout)) + bout
//           (3) f16 MFMA for encoder GEMM (268MB W2 read is the HBM floor) and layer-1 GEMM

#define B_    64
#define EIN   64
#define EHID  256
#define NN    2048
#define GH    128
#define NG    (NN*GH)          // 262144
#define LN_EPS 1e-5f
#define C3    28               // nodes per k_gcn1 block (ext rows = 32 = 2 MFMA m-groups)
#define C4    128              // nodes per k_gcn2 block

typedef _Float16 f16;
typedef _Float16 f16x8 __attribute__((ext_vector_type(8)));
typedef _Float16 f16x4 __attribute__((ext_vector_type(4)));
typedef float    f32x4 __attribute__((ext_vector_type(4)));
typedef unsigned int u32;

__device__ __forceinline__ float wred(float v) {
#pragma unroll
    for (int off = 32; off > 0; off >>= 1) v += __shfl_xor(v, off, 64);
    return v;
}

// ---------------- K1: h1 = relu(x@W1+b1) (f16), Wg1^T (f16), v2 = Wg2@Wout ----
__global__ __launch_bounds__(256) void k_prep(
    const float* __restrict__ x,  const float* __restrict__ W1, const float* __restrict__ b1,
    const float* __restrict__ Wg1,const float* __restrict__ Wg2,const float* __restrict__ Wout,
    f16* __restrict__ h1h, f16* __restrict__ wg1T, float* __restrict__ v2)
{
    int bid = blockIdx.x, tid = threadIdx.x;
    if (bid < 64) {
        int b = bid, j = tid;
        float acc = b1[j];
#pragma unroll 8
        for (int k = 0; k < EIN; ++k) acc = fmaf(x[b*EIN + k], W1[k*EHID + j], acc);
        h1h[b*EHID + j] = (f16)fmaxf(acc, 0.f);
    } else if (bid == 64) {
        if (tid < GH) {
            float s = 0.f;
            for (int j = 0; j < GH; ++j) s = fmaf(Wg2[tid*GH + j], Wout[j], s);
            v2[tid] = s;
        }
    } else {
        for (int i = tid; i < GH*GH; i += 256) {
            int n = i >> 7, k = i & 127;          // wg1T[n][k] = Wg1[k][n]
            wg1T[i] = (f16)Wg1[k*GH + n];
        }
    }
}

// ---------------- K2: out0 = h1 @ W2 + b2  (M=64,K=256,N=262144), f16 out ----
__global__ __launch_bounds__(256) void k_enc(
    const float* __restrict__ W2, const float* __restrict__ b2,
    const f16* __restrict__ h1h, f16* __restrict__ out0)
{
    __shared__ f16 h1s[64][264];   // pad 8: rows 528B (16B-aligned), 2-way bank alias only
    int tid = threadIdx.x;
    const u32* h1u = (const u32*)h1h;
    for (int i = tid; i < 8192; i += 256)
        ((u32*)h1s)[(i >> 7)*132 + (i & 127)] = h1u[i];
    __syncthreads();

    int L = tid & 63, wv = tid >> 6, hi = L >> 4, lo = L & 15;
    int c_lane = blockIdx.x*64 + wv*16 + lo;
    const float* Wp = W2 + c_lane;

    f32x4 z = {0.f, 0.f, 0.f, 0.f};
    f32x4 acc[4];
#pragma unroll
    for (int bg = 0; bg < 4; ++bg) acc[bg] = z;

#pragma unroll
    for (int kk = 0; kk < 8; ++kk) {
        f16x8 bf;
        const float* wr = Wp + (size_t)(kk*32 + hi*8) * NG;
#pragma unroll
        for (int j = 0; j < 8; ++j) bf[j] = (f16)wr[(size_t)j * NG];
#pragma unroll
        for (int bg = 0; bg < 4; ++bg) {
            f16x8 af = *(const f16x8*)&h1s[bg*16 + lo][kk*32 + hi*8];
            acc[bg] = __builtin_amdgcn_mfma_f32_16x16x32_f16(af, bf, acc[bg], 0, 0, 0);
        }
    }
    float bv = b2[c_lane];
#pragma unroll
    for (int bg = 0; bg < 4; ++bg)
#pragma unroll
        for (int r = 0; r < 4; ++r) {
            int brow = bg*16 + hi*4 + r;          // C/D: row=(lane>>4)*4+reg, col=lane&15
            out0[(size_t)brow * NG + c_lane] = (f16)(acc[bg][r] + bv);
        }
}

// ---------------- K3: out1 = out0 + A (x) (LN1(out0) @ Wg1), per (b, 28-node chunk) ----
__global__ __launch_bounds__(256) void k_gcn1(
    const float* __restrict__ A_hat, const float* __restrict__ ln_g1, const float* __restrict__ ln_b1,
    const f16* __restrict__ wg1T, const f16* __restrict__ out0, f16* __restrict__ out1)
{
    __shared__ f16 out0_s[32][132];
    __shared__ f16 h0s[32][136];         // A-operand staging, +8 pad
    __shared__ f16 wg1s[GH*GH];          // B-operand, XOR-swizzled 16B chunks
    __shared__ f16 wx0_s[32][132];
    __shared__ float g1s[GH], b1s[GH];
    __shared__ float clo_s[C3], chi_s[C3];

    int tid = threadIdx.x;
    int n0 = blockIdx.x * C3;
    int b  = blockIdx.y;

    // stage Wg1^T swizzled: chunk cs=kp>>2 stored at cs^(n&15)
    {
        const u32* wu = (const u32*)wg1T;
        u32* wd = (u32*)wg1s;
        for (int i = tid; i < 8192; i += 256) {
            int n = i >> 6, kp = i & 63;
            int cs = (kp >> 2) ^ (n & 15);
            wd[n*64 + cs*4 + (kp & 3)] = wu[i];
        }
    }
    // stage out0 rows (nodes n0-2 .. n0+29), zero outside
    for (int i = tid; i < 32*32; i += 256) {
        int r = i >> 5, gv = i & 31;
        int n = n0 - 2 + r;
        f16x4 v = {0, 0, 0, 0};
        if (n >= 0 && n < NN) v = *(const f16x4*)(out0 + ((size_t)b*NN + n)*GH + gv*4);
        *(f16x4*)&out0_s[r][gv*4] = v;
    }
    if (tid < GH) { g1s[tid] = ln_g1[tid]; b1s[tid] = ln_b1[tid]; }
    else if (tid < GH + C3) {
        int t = tid - GH, n = n0 + t;
        float cl = 0.f, ch = 0.f;
        if (n < NN) {
            if (n >= 1)    cl = A_hat[(size_t)n*NN + (n-1)];
            if (n <= NN-2) ch = A_hat[(size_t)n*NN + (n+1)];
        }
        clo_s[t] = cl; chi_s[t] = ch;
    }
    __syncthreads();

    int L = tid & 63, wv = tid >> 6, hi = L >> 4, lo = L & 15;
    // LN1: one wave per row
    for (int r = wv; r < 32; r += 4) {
        float x0 = (float)out0_s[r][2*L], x1 = (float)out0_s[r][2*L+1];
        float s  = wred(x0 + x1);
        float q  = wred(x0*x0 + x1*x1);
        float mu = s * (1.f/128.f);
        float inv = rsqrtf(q*(1.f/128.f) - mu*mu + LN_EPS);
        h0s[r][2*L]   = (f16)((x0 - mu)*inv*g1s[2*L]   + b1s[2*L]);
        h0s[r][2*L+1] = (f16)((x1 - mu)*inv*g1s[2*L+1] + b1s[2*L+1]);
    }
    __syncthreads();

    // Wx0 = h0 @ Wg1 : M=32 ext-rows, N=128, K=128. Wave wv -> cols [wv*32, wv*32+32)
    f32x4 z = {0.f, 0.f, 0.f, 0.f};
    f32x4 acc[2][2];
#pragma unroll
    for (int mg = 0; mg < 2; ++mg)
#pragma unroll
        for (int nt = 0; nt < 2; ++nt) acc[mg][nt] = z;

#pragma unroll
    for (int kk = 0; kk < 4; ++kk) {
        f16x8 af[2], bfr[2];
#pragma unroll
        for (int mg = 0; mg < 2; ++mg)
            af[mg] = *(const f16x8*)&h0s[mg*16 + lo][kk*32 + hi*8];
#pragma unroll
        for (int nt = 0; nt < 2; ++nt) {
            int n  = wv*32 + nt*16 + lo;        // n&15 == lo
            int cs = (kk*4 + hi) ^ lo;
            bfr[nt] = *(const f16x8*)&wg1s[n*GH + cs*8];
        }
#pragma unroll
        for (int mg = 0; mg < 2; ++mg)
#pragma unroll
            for (int nt = 0; nt < 2; ++nt)
                acc[mg][nt] = __builtin_amdgcn_mfma_f32_16x16x32_f16(af[mg], bfr[nt], acc[mg][nt], 0, 0, 0);
    }
#pragma unroll
    for (int mg = 0; mg < 2; ++mg)
#pragma unroll
        for (int nt = 0; nt < 2; ++nt)
#pragma unroll
            for (int r = 0; r < 4; ++r)
                wx0_s[mg*16 + hi*4 + r][wv*32 + nt*16 + lo] = (f16)acc[mg][nt][r];
    __syncthreads();

    // out1[n] = out0[n] + clo*Wx0[n-1] + chi*Wx0[n+1]   (node n ext-row = t+2)
    for (int i = tid; i < C3*GH; i += 256) {
        int t = i >> 7, g = i & 127;
        int n = n0 + t;
        if (n < NN) {
            float val = (float)out0_s[t+2][g]
                      + clo_s[t]*(float)wx0_s[t+1][g]
                      + chi_s[t]*(float)wx0_s[t+3][g];
            out1[((size_t)b*NN + n)*GH + g] = (f16)val;
        }
    }
}

// ---------------- K4: y = out1@Wout + bout + A (x) (LN2(out1) . v2) ----
__global__ __launch_bounds__(256) void k_gcn2(
    const float* __restrict__ A_hat, const float* __restrict__ ln_g2, const float* __restrict__ ln_b2,
    const float* __restrict__ Wout, const float* __restrict__ bout, const float* __restrict__ v2,
    const f16* __restrict__ out1, float* __restrict__ y)
{
    __shared__ f16 out1_s[C4+2][132];
    __shared__ float g2s[GH], b2s[GH], v2s[GH], wos[GH];
    __shared__ float ss[C4+2], yr[C4+2];

    int tid = threadIdx.x;
    int n0 = blockIdx.x * C4;
    int b  = blockIdx.y;

    for (int i = tid; i < (C4+2)*32; i += 256) {
        int r = i >> 5, gv = i & 31;
        int n = n0 - 1 + r;
        f16x4 v = {0, 0, 0, 0};
        if (n >= 0 && n < NN) v = *(const f16x4*)(out1 + ((size_t)b*NN + n)*GH + gv*4);
        *(f16x4*)&out1_s[r][gv*4] = v;
    }
    if (tid < GH) { g2s[tid] = ln_g2[tid]; b2s[tid] = ln_b2[tid]; v2s[tid] = v2[tid]; wos[tid] = Wout[tid]; }
    __syncthreads();

    int L = tid & 63, wv = tid >> 6;
    for (int r = wv; r < C4+2; r += 4) {
        float x0 = (float)out1_s[r][2*L], x1 = (float)out1_s[r][2*L+1];
        float s  = wred(x0 + x1);
        float q  = wred(x0*x0 + x1*x1);
        float mu = s * (1.f/128.f);
        float inv = rsqrtf(q*(1.f/128.f) - mu*mu + LN_EPS);
        float h0 = (x0 - mu)*inv*g2s[2*L]   + b2s[2*L];
        float h1 = (x1 - mu)*inv*g2s[2*L+1] + b2s[2*L+1];
        float sp = wred(h0*v2s[2*L] + h1*v2s[2*L+1]);   // LN2(out1) . v2
        float yp = wred(x0*wos[2*L] + x1*wos[2*L+1]);   // out1 . Wout
        if (L == 0) { ss[r] = sp; yr[r] = yp; }
    }
    __syncthreads();

    if (tid < C4) {
        int n = n0 + tid, r = tid + 1;
        float cl = (n >= 1)    ? A_hat[(size_t)n*NN + (n-1)] : 0.f;
        float ch = (n <= NN-2) ? A_hat[(size_t)n*NN + (n+1)] : 0.f;
        y[(size_t)b*NN + n] = yr[r] + bout[0] + cl*ss[r-1] + ch*ss[r+1];
    }
}

// ---------------- launcher ----------------
extern "C" void kernel_launch(void* const* d_in, const int* in_sizes, int n_in,
                              void* d_out, int out_size, void* d_ws, size_t ws_size,
                              hipStream_t stream)
{
    (void)in_sizes; (void)n_in; (void)out_size; (void)ws_size;
    const float* x    = (const float*)d_in[0];
    const float* A_hat= (const float*)d_in[1];
    const float* W1   = (const float*)d_in[2];
    const float* b1   = (const float*)d_in[3];
    const float* W2   = (const float*)d_in[4];
    const float* b2   = (const float*)d_in[5];
    const float* Wg1  = (const float*)d_in[6];
    const float* Wg2  = (const float*)d_in[7];
    const float* g1   = (const float*)d_in[8];
    const float* lb1  = (const float*)d_in[9];
    const float* g2   = (const float*)d_in[10];
    const float* lb2  = (const float*)d_in[11];
    const float* Wout = (const float*)d_in[12];
    const float* bout = (const float*)d_in[13];
    float* y = (float*)d_out;

    // ws layout: [0,32K) h1 f16 | [32K,64K) Wg1^T f16 | [64K,+512) v2 f32 |
    //            [1M, 1M+32M) out0 f16 | [1M+32M, 1M+64M) out1 f16   (total ~68.2 MB)
    char* ws = (char*)d_ws;
    f16*   h1h  = (f16*)(ws + 0);
    f16*   wg1T = (f16*)(ws + 32768);
    float* v2   = (float*)(ws + 65536);
    f16*   out0 = (f16*)(ws + (1u << 20));
    f16*   out1 = (f16*)(ws + (1u << 20) + (size_t)B_*NG*2);

    k_prep<<<dim3(66),                    256, 0, stream>>>(x, W1, b1, Wg1, Wg2, Wout, h1h, wg1T, v2);
    k_enc <<<dim3(NG/64),                 256, 0, stream>>>(W2, b2, h1h, out0);
    k_gcn1<<<dim3((NN + C3 - 1)/C3, B_),  256, 0, stream>>>(A_hat, g1, lb1, wg1T, out0, out1);
    k_gcn2<<<dim3(NN/C4, B_),             256, 0, stream>>>(A_hat, g2, lb2, Wout, bout, v2, out1, y);
}

// Round 2
// 500.078 us; speedup vs baseline: 1.0739x; 1.0739x over previous
//
#include <hip/hip_runtime.h>

// ChainGNN: B=64, ENC_IN=64, ENC_HID=256, N=2048, GH=128
// Exploits: (1) A_hat tridiagonal (chain) -> neighbor mix, not dense matmul
//           (2) layer-2 collapse: y = out1@Wout + A*(LN(out1)@(Wg2@Wout)) + bout
//           (3) f16 MFMA for encoder GEMM (268MB W2 read is the HBM floor) and layer-1 GEMM
// R2: k_enc streams W2 via global_load_lds (512B-contiguous rows, double-buffered LDS);
//     k_gcn1 reads Wg1^T fragments from L2 instead of staging to LDS.

#define B_    64
#define EIN   64
#define EHID  256
#define NN    2048
#define GH    128
#define NG    (NN*GH)          // 262144
#define LN_EPS 1e-5f
#define C3    28               // nodes per k_gcn1 block (ext rows = 32 = 2 MFMA m-groups)
#define C4    128              // nodes per k_gcn2 block

typedef _Float16 f16;
typedef _Float16 f16x8 __attribute__((ext_vector_type(8)));
typedef _Float16 f16x4 __attribute__((ext_vector_type(4)));
typedef float    f32x4 __attribute__((ext_vector_type(4)));
typedef unsigned int u32;

#define AS1 __attribute__((address_space(1)))
#define AS3 __attribute__((address_space(3)))

__device__ __forceinline__ float wred(float v) {
#pragma unroll
    for (int off = 32; off > 0; off >>= 1) v += __shfl_xor(v, off, 64);
    return v;
}

// ---------------- K1: h1 = relu(x@W1+b1) (f16), Wg1^T (f16), v2 = Wg2@Wout ----
__global__ __launch_bounds__(256) void k_prep(
    const float* __restrict__ x,  const float* __restrict__ W1, const float* __restrict__ b1,
    const float* __restrict__ Wg1,const float* __restrict__ Wg2,const float* __restrict__ Wout,
    f16* __restrict__ h1h, f16* __restrict__ wg1T, float* __restrict__ v2)
{
    int bid = blockIdx.x, tid = threadIdx.x;
    if (bid < 64) {
        int b = bid, j = tid;
        float acc = b1[j];
#pragma unroll 8
        for (int k = 0; k < EIN; ++k) acc = fmaf(x[b*EIN + k], W1[k*EHID + j], acc);
        h1h[b*EHID + j] = (f16)fmaxf(acc, 0.f);
    } else if (bid == 64) {
        if (tid < GH) {
            float s = 0.f;
            for (int j = 0; j < GH; ++j) s = fmaf(Wg2[tid*GH + j], Wout[j], s);
            v2[tid] = s;
        }
    } else {
        for (int i = tid; i < GH*GH; i += 256) {
            int n = i >> 7, k = i & 127;          // wg1T[n][k] = Wg1[k][n]
            wg1T[i] = (f16)Wg1[k*GH + n];
        }
    }
}

// ---------------- K2: out0 = h1 @ W2 + b2  (M=64,K=256,N=262144), f16 out ----
// Block: 128 cols, 256 threads. W2 staged 32x128 fp32 tiles, double-buffered,
// via global_load_lds dwordx4 (512B contiguous per row -> DRAM-page friendly).
__global__ __launch_bounds__(256) void k_enc(
    const float* __restrict__ W2, const float* __restrict__ b2,
    const f16* __restrict__ h1h, f16* __restrict__ out0)
{
    __shared__ float w2s[2][32][128];     // 2 x 16 KB

    int tid = threadIdx.x;
    int L = tid & 63, wv = tid >> 6, hi = L >> 4, lo = L & 15;
    int c0 = blockIdx.x * 128;
    int lrow = L >> 5, lcol4 = (L & 31) * 4;

    // stage tile kk into buffer nb: 4 instrs/wave, 2 rows per instr
    auto stage = [&](int kk, int nb) {
#pragma unroll
        for (int s = 0; s < 4; ++s) {
            int r = wv*8 + s*2;
            const float* gp = W2 + (size_t)(kk*32 + r + lrow) * NG + c0 + lcol4;
            __builtin_amdgcn_global_load_lds((const AS1 void*)gp,
                                             (AS3 void*)&w2s[nb][r][0], 16, 0, 0);
        }
    };

    stage(0, 0);

    f32x4 acc[4][2];
#pragma unroll
    for (int bg = 0; bg < 4; ++bg)
#pragma unroll
        for (int t = 0; t < 2; ++t) acc[bg][t] = f32x4{0.f, 0.f, 0.f, 0.f};

#pragma unroll
    for (int kk = 0; kk < 8; ++kk) {
        __syncthreads();                       // drains vmcnt: tile kk resident
        if (kk < 7) stage(kk + 1, (kk + 1) & 1);

        const float (*wb)[128] = w2s[kk & 1];
        f16x8 bf[2];
#pragma unroll
        for (int t = 0; t < 2; ++t)
#pragma unroll
            for (int j = 0; j < 8; ++j)
                bf[t][j] = (f16)wb[hi*8 + j][wv*32 + t*16 + lo];

        f16x8 af[4];
#pragma unroll
        for (int bg = 0; bg < 4; ++bg)
            af[bg] = *(const f16x8*)(h1h + ((bg*16 + lo) << 8) + kk*32 + hi*8);

#pragma unroll
        for (int bg = 0; bg < 4; ++bg)
#pragma unroll
            for (int t = 0; t < 2; ++t)
                acc[bg][t] = __builtin_amdgcn_mfma_f32_16x16x32_f16(af[bg], bf[t], acc[bg][t], 0, 0, 0);
    }

    float bv[2];
#pragma unroll
    for (int t = 0; t < 2; ++t) bv[t] = b2[c0 + wv*32 + t*16 + lo];
#pragma unroll
    for (int bg = 0; bg < 4; ++bg)
#pragma unroll
        for (int t = 0; t < 2; ++t)
#pragma unroll
            for (int r = 0; r < 4; ++r) {
                int brow = bg*16 + hi*4 + r;      // C/D: row=(lane>>4)*4+reg, col=lane&15
                out0[(size_t)brow * NG + c0 + wv*32 + t*16 + lo] = (f16)(acc[bg][t][r] + bv[t]);
            }
}

// ---------------- K3: out1 = out0 + A (x) (LN1(out0) @ Wg1), per (b, 28-node chunk) ----
__global__ __launch_bounds__(256) void k_gcn1(
    const float* __restrict__ A_hat, const float* __restrict__ ln_g1, const float* __restrict__ ln_b1,
    const f16* __restrict__ wg1T, const f16* __restrict__ out0, f16* __restrict__ out1)
{
    __shared__ f16 out0_s[32][132];
    __shared__ f16 h0s[32][136];         // A-operand staging, +8 pad
    __shared__ f16 wx0_s[32][132];
    __shared__ float g1s[GH], b1s[GH];
    __shared__ float clo_s[C3], chi_s[C3];

    int tid = threadIdx.x;
    int n0 = blockIdx.x * C3;
    int b  = blockIdx.y;

    // stage out0 rows (nodes n0-2 .. n0+29), zero outside
    for (int i = tid; i < 32*32; i += 256) {
        int r = i >> 5, gv = i & 31;
        int n = n0 - 2 + r;
        f16x4 v = {0, 0, 0, 0};
        if (n >= 0 && n < NN) v = *(const f16x4*)(out0 + ((size_t)b*NN + n)*GH + gv*4);
        *(f16x4*)&out0_s[r][gv*4] = v;
    }
    if (tid < GH) { g1s[tid] = ln_g1[tid]; b1s[tid] = ln_b1[tid]; }
    else if (tid < GH + C3) {
        int t = tid - GH, n = n0 + t;
        float cl = 0.f, ch = 0.f;
        if (n < NN) {
            if (n >= 1)    cl = A_hat[(size_t)n*NN + (n-1)];
            if (n <= NN-2) ch = A_hat[(size_t)n*NN + (n+1)];
        }
        clo_s[t] = cl; chi_s[t] = ch;
    }
    __syncthreads();

    int L = tid & 63, wv = tid >> 6, hi = L >> 4, lo = L & 15;
    // LN1: one wave per row
    for (int r = wv; r < 32; r += 4) {
        float x0 = (float)out0_s[r][2*L], x1 = (float)out0_s[r][2*L+1];
        float s  = wred(x0 + x1);
        float q  = wred(x0*x0 + x1*x1);
        float mu = s * (1.f/128.f);
        float inv = rsqrtf(q*(1.f/128.f) - mu*mu + LN_EPS);
        h0s[r][2*L]   = (f16)((x0 - mu)*inv*g1s[2*L]   + b1s[2*L]);
        h0s[r][2*L+1] = (f16)((x1 - mu)*inv*g1s[2*L+1] + b1s[2*L+1]);
    }
    __syncthreads();

    // Wx0 = h0 @ Wg1 : M=32 ext-rows, N=128, K=128. Wave wv -> cols [wv*32, wv*32+32)
    // B fragments read straight from global wg1T (32 KB, L1/L2-hot).
    f32x4 z = {0.f, 0.f, 0.f, 0.f};
    f32x4 acc[2][2];
#pragma unroll
    for (int mg = 0; mg < 2; ++mg)
#pragma unroll
        for (int nt = 0; nt < 2; ++nt) acc[mg][nt] = z;

#pragma unroll
    for (int kk = 0; kk < 4; ++kk) {
        f16x8 af[2], bfr[2];
#pragma unroll
        for (int mg = 0; mg < 2; ++mg)
            af[mg] = *(const f16x8*)&h0s[mg*16 + lo][kk*32 + hi*8];
#pragma unroll
        for (int nt = 0; nt < 2; ++nt) {
            int n = wv*32 + nt*16 + lo;
            bfr[nt] = *(const f16x8*)(wg1T + n*GH + kk*32 + hi*8);
        }
#pragma unroll
        for (int mg = 0; mg < 2; ++mg)
#pragma unroll
            for (int nt = 0; nt < 2; ++nt)
                acc[mg][nt] = __builtin_amdgcn_mfma_f32_16x16x32_f16(af[mg], bfr[nt], acc[mg][nt], 0, 0, 0);
    }
#pragma unroll
    for (int mg = 0; mg < 2; ++mg)
#pragma unroll
        for (int nt = 0; nt < 2; ++nt)
#pragma unroll
            for (int r = 0; r < 4; ++r)
                wx0_s[mg*16 + hi*4 + r][wv*32 + nt*16 + lo] = (f16)acc[mg][nt][r];
    __syncthreads();

    // out1[n] = out0[n] + clo*Wx0[n-1] + chi*Wx0[n+1]   (node n ext-row = t+2)
    for (int i = tid; i < C3*GH; i += 256) {
        int t = i >> 7, g = i & 127;
        int n = n0 + t;
        if (n < NN) {
            float val = (float)out0_s[t+2][g]
                      + clo_s[t]*(float)wx0_s[t+1][g]
                      + chi_s[t]*(float)wx0_s[t+3][g];
            out1[((size_t)b*NN + n)*GH + g] = (f16)val;
        }
    }
}

// ---------------- K4: y = out1@Wout + bout + A (x) (LN2(out1) . v2) ----
__global__ __launch_bounds__(256) void k_gcn2(
    const float* __restrict__ A_hat, const float* __restrict__ ln_g2, const float* __restrict__ ln_b2,
    const float* __restrict__ Wout, const float* __restrict__ bout, const float* __restrict__ v2,
    const f16* __restrict__ out1, float* __restrict__ y)
{
    __shared__ f16 out1_s[C4+2][132];
    __shared__ float g2s[GH], b2s[GH], v2s[GH], wos[GH];
    __shared__ float ss[C4+2], yr[C4+2];

    int tid = threadIdx.x;
    int n0 = blockIdx.x * C4;
    int b  = blockIdx.y;

    for (int i = tid; i < (C4+2)*32; i += 256) {
        int r = i >> 5, gv = i & 31;
        int n = n0 - 1 + r;
        f16x4 v = {0, 0, 0, 0};
        if (n >= 0 && n < NN) v = *(const f16x4*)(out1 + ((size_t)b*NN + n)*GH + gv*4);
        *(f16x4*)&out1_s[r][gv*4] = v;
    }
    if (tid < GH) { g2s[tid] = ln_g2[tid]; b2s[tid] = ln_b2[tid]; v2s[tid] = v2[tid]; wos[tid] = Wout[tid]; }
    __syncthreads();

    int L = tid & 63, wv = tid >> 6;
    for (int r = wv; r < C4+2; r += 4) {
        float x0 = (float)out1_s[r][2*L], x1 = (float)out1_s[r][2*L+1];
        float s  = wred(x0 + x1);
        float q  = wred(x0*x0 + x1*x1);
        float mu = s * (1.f/128.f);
        float inv = rsqrtf(q*(1.f/128.f) - mu*mu + LN_EPS);
        float h0 = (x0 - mu)*inv*g2s[2*L]   + b2s[2*L];
        float h1 = (x1 - mu)*inv*g2s[2*L+1] + b2s[2*L+1];
        float sp = wred(h0*v2s[2*L] + h1*v2s[2*L+1]);   // LN2(out1) . v2
        float yp = wred(x0*wos[2*L] + x1*wos[2*L+1]);   // out1 . Wout
        if (L == 0) { ss[r] = sp; yr[r] = yp; }
    }
    __syncthreads();

    if (tid < C4) {
        int n = n0 + tid, r = tid + 1;
        float cl = (n >= 1)    ? A_hat[(size_t)n*NN + (n-1)] : 0.f;
        float ch = (n <= NN-2) ? A_hat[(size_t)n*NN + (n+1)] : 0.f;
        y[(size_t)b*NN + n] = yr[r] + bout[0] + cl*ss[r-1] + ch*ss[r+1];
    }
}

// ---------------- launcher ----------------
extern "C" void kernel_launch(void* const* d_in, const int* in_sizes, int n_in,
                              void* d_out, int out_size, void* d_ws, size_t ws_size,
                              hipStream_t stream)
{
    (void)in_sizes; (void)n_in; (void)out_size; (void)ws_size;
    const float* x    = (const float*)d_in[0];
    const float* A_hat= (const float*)d_in[1];
    const float* W1   = (const float*)d_in[2];
    const float* b1   = (const float*)d_in[3];
    const float* W2   = (const float*)d_in[4];
    const float* b2   = (const float*)d_in[5];
    const float* Wg1  = (const float*)d_in[6];
    const float* Wg2  = (const float*)d_in[7];
    const float* g1   = (const float*)d_in[8];
    const float* lb1  = (const float*)d_in[9];
    const float* g2   = (const float*)d_in[10];
    const float* lb2  = (const float*)d_in[11];
    const float* Wout = (const float*)d_in[12];
    const float* bout = (const float*)d_in[13];
    float* y = (float*)d_out;

    // ws layout: [0,32K) h1 f16 | [32K,64K) Wg1^T f16 | [64K,+512) v2 f32 |
    //            [1M, 1M+32M) out0 f16 | [1M+32M, 1M+64M) out1 f16   (total ~68.2 MB)
    char* ws = (char*)d_ws;
    f16*   h1h  = (f16*)(ws + 0);
    f16*   wg1T = (f16*)(ws + 32768);
    float* v2   = (float*)(ws + 65536);
    f16*   out0 = (f16*)(ws + (1u << 20));
    f16*   out1 = (f16*)(ws + (1u << 20) + (size_t)B_*NG*2);

    k_prep<<<dim3(66),                    256, 0, stream>>>(x, W1, b1, Wg1, Wg2, Wout, h1h, wg1T, v2);
    k_enc <<<dim3(NG/128),                256, 0, stream>>>(W2, b2, h1h, out0);
    k_gcn1<<<dim3((NN + C3 - 1)/C3, B_),  256, 0, stream>>>(A_hat, g1, lb1, wg1T, out0, out1);
    k_gcn2<<<dim3(NN/C4, B_),             256, 0, stream>>>(A_hat, g2, lb2, Wout, bout, v2, out1, y);
}

// Round 3
// 486.157 us; speedup vs baseline: 1.1046x; 1.0286x over previous
//
#include <hip/hip_runtime.h>

// ChainGNN: B=64, ENC_IN=64, ENC_HID=256, N=2048, GH=128
// Exploits: (1) A_hat tridiagonal (chain) -> neighbor mix, not dense matmul
//           (2) layer-2 collapse: y = out1@Wout + A*(LN(out1)@(Wg2@Wout)) + bout
//           (3) f16 MFMA for encoder GEMM (268MB W2 read is the HBM floor) and layer-1 GEMM
// R3: gcn1+gcn2 fused (out1 never materialized, saves 64MB traffic + a launch);
//     k_enc LDS tile group-padded (4 rows + 16B) -> conflict-free fragment reads;
//     A_hat off-diagonals precomputed as dense clo/chi vectors.

#define B_    64
#define EIN   64
#define EHID  256
#define NN    2048
#define GH    128
#define NG    (NN*GH)          // 262144
#define LN_EPS 1e-5f
#define C3    28               // nodes per k_gcn block (ext rows = 32 = 2 MFMA m-groups)

typedef _Float16 f16;
typedef _Float16 f16x8 __attribute__((ext_vector_type(8)));
typedef _Float16 f16x4 __attribute__((ext_vector_type(4)));
typedef float    f32x4 __attribute__((ext_vector_type(4)));
typedef unsigned int u32;

#define AS1 __attribute__((address_space(1)))
#define AS3 __attribute__((address_space(3)))

__device__ __forceinline__ float wred(float v) {
#pragma unroll
    for (int off = 32; off > 0; off >>= 1) v += __shfl_xor(v, off, 64);
    return v;
}

// ---- K1: h1=relu(x@W1+b1) f16 | Wg1^T f16 | v2=Wg2@Wout | clo/chi off-diagonals ----
__global__ __launch_bounds__(256) void k_prep(
    const float* __restrict__ x,  const float* __restrict__ W1, const float* __restrict__ b1,
    const float* __restrict__ Wg1,const float* __restrict__ Wg2,const float* __restrict__ Wout,
    const float* __restrict__ A_hat,
    f16* __restrict__ h1h, f16* __restrict__ wg1T, float* __restrict__ v2,
    float* __restrict__ clo, float* __restrict__ chi)
{
    int bid = blockIdx.x, tid = threadIdx.x;
    if (bid < 64) {
        int b = bid, j = tid;
        float acc = b1[j];
#pragma unroll 8
        for (int k = 0; k < EIN; ++k) acc = fmaf(x[b*EIN + k], W1[k*EHID + j], acc);
        h1h[b*EHID + j] = (f16)fmaxf(acc, 0.f);
    } else if (bid == 64) {
        if (tid < GH) {
            float s = 0.f;
            for (int j = 0; j < GH; ++j) s = fmaf(Wg2[tid*GH + j], Wout[j], s);
            v2[tid] = s;
        }
    } else if (bid == 65) {
        for (int i = tid; i < GH*GH; i += 256) {
            int n = i >> 7, k = i & 127;          // wg1T[n][k] = Wg1[k][n]
            wg1T[i] = (f16)Wg1[k*GH + n];
        }
    } else {
        int n = (bid - 66) * 256 + tid;           // bids 66..73 cover n = 0..2047
        clo[n] = (n >= 1)    ? A_hat[(size_t)n*NN + (n-1)] : 0.f;
        chi[n] = (n <= NN-2) ? A_hat[(size_t)n*NN + (n+1)] : 0.f;
    }
}

// ---- K2: out0 = h1 @ W2 + b2  (M=64,K=256,N=262144), f16 out ----
// 128 cols/block. W2 staged 32x128 fp32 double-buffered via global_load_lds dwordx4.
// LDS layout: groups of 4 rows (2048B) + 16B pad -> fragment reads 2 lanes/bank (free).
__global__ __launch_bounds__(256) void k_enc(
    const float* __restrict__ W2, const float* __restrict__ b2,
    const f16* __restrict__ h1h, f16* __restrict__ out0)
{
    __shared__ float w2s[2][4128];        // 8 groups * (4*128 + 4 pad floats)

    int tid = threadIdx.x;
    int L = tid & 63, wv = tid >> 6, hi = L >> 4, lo = L & 15;
    int c0 = blockIdx.x * 128;
    int lrow = L >> 5, lcol4 = (L & 31) * 4;

    auto stage = [&](int kk, int nb) {
#pragma unroll
        for (int s = 0; s < 4; ++s) {
            int r = wv*8 + s*2;                                 // even; r&3 in {0,2}
            const float* gp = W2 + (size_t)(kk*32 + r + lrow) * NG + c0 + lcol4;
            float* ldst = &w2s[nb][(r >> 2)*516 + (r & 3)*128]; // rows r,r+1 contiguous
            __builtin_amdgcn_global_load_lds((const AS1 void*)gp, (AS3 void*)ldst, 16, 0, 0);
        }
    };

    stage(0, 0);

    f32x4 acc[4][2];
#pragma unroll
    for (int bg = 0; bg < 4; ++bg)
#pragma unroll
        for (int t = 0; t < 2; ++t) acc[bg][t] = f32x4{0.f, 0.f, 0.f, 0.f};

#pragma unroll
    for (int kk = 0; kk < 8; ++kk) {
        __syncthreads();                       // drains vmcnt: tile kk resident
        if (kk < 7) stage(kk + 1, (kk + 1) & 1);

        const float* wb = w2s[kk & 1];
        f16x8 bf[2];
#pragma unroll
        for (int t = 0; t < 2; ++t)
#pragma unroll
            for (int j = 0; j < 8; ++j)
                bf[t][j] = (f16)wb[(hi*2 + (j >> 2))*516 + (j & 3)*128 + wv*32 + t*16 + lo];

        f16x8 af[4];
#pragma unroll
        for (int bg = 0; bg < 4; ++bg)
            af[bg] = *(const f16x8*)(h1h + ((bg*16 + lo) << 8) + kk*32 + hi*8);

#pragma unroll
        for (int bg = 0; bg < 4; ++bg)
#pragma unroll
            for (int t = 0; t < 2; ++t)
                acc[bg][t] = __builtin_amdgcn_mfma_f32_16x16x32_f16(af[bg], bf[t], acc[bg][t], 0, 0, 0);
    }

    float bv[2];
#pragma unroll
    for (int t = 0; t < 2; ++t) bv[t] = b2[c0 + wv*32 + t*16 + lo];
#pragma unroll
    for (int bg = 0; bg < 4; ++bg)
#pragma unroll
        for (int t = 0; t < 2; ++t)
#pragma unroll
            for (int r = 0; r < 4; ++r) {
                int brow = bg*16 + hi*4 + r;      // C/D: row=(lane>>4)*4+reg, col=lane&15
                out0[(size_t)brow * NG + c0 + wv*32 + t*16 + lo] = (f16)(acc[bg][t][r] + bv[t]);
            }
}

// ---- K3 (fused GCN1+GCN2): per (b, 28-node chunk) ->
//   Wx0 = LN1(out0)@Wg1 (ext 32 rows), out1 = out0 + mix(Wx0) (rows 1..30, in LDS),
//   s2 = LN2(out1).v2, yr = out1.Wout, y = yr + bout + mix(s2).
__global__ __launch_bounds__(256) void k_gcn(
    const float* __restrict__ clo, const float* __restrict__ chi,
    const float* __restrict__ ln_g1, const float* __restrict__ ln_b1,
    const float* __restrict__ ln_g2, const float* __restrict__ ln_b2,
    const float* __restrict__ Wout, const float* __restrict__ bout,
    const float* __restrict__ v2, const f16* __restrict__ wg1T,
    const f16* __restrict__ out0, float* __restrict__ y)
{
    __shared__ f16 out0_s[32][132];      // ext rows: nodes n0-2 .. n0+29 (becomes out1 in place)
    __shared__ f16 h0s[32][136];
    __shared__ f16 wx0_s[32][132];
    __shared__ float g1s[GH], b1s[GH], g2s[GH], b2s[GH], v2s[GH], wos[GH];
    __shared__ float cls[32], chs[32];
    __shared__ float ss[32], yrs[32];

    int tid = threadIdx.x;
    int n0 = blockIdx.x * C3;
    int b  = blockIdx.y;

    for (int i = tid; i < 32*32; i += 256) {
        int r = i >> 5, gv = i & 31;
        int n = n0 - 2 + r;
        f16x4 v = {0, 0, 0, 0};
        if (n >= 0 && n < NN) v = *(const f16x4*)(out0 + ((size_t)b*NN + n)*GH + gv*4);
        *(f16x4*)&out0_s[r][gv*4] = v;
    }
    if (tid < GH) {
        g1s[tid] = ln_g1[tid]; b1s[tid] = ln_b1[tid];
        g2s[tid] = ln_g2[tid]; b2s[tid] = ln_b2[tid];
        v2s[tid] = v2[tid];    wos[tid] = Wout[tid];
    } else if (tid < GH + 32) {
        int r = tid - GH, n = n0 - 2 + r;
        bool ok = (n >= 0 && n < NN);
        cls[r] = ok ? clo[n] : 0.f;
        chs[r] = ok ? chi[n] : 0.f;
    }
    __syncthreads();

    int L = tid & 63, wv = tid >> 6, hi = L >> 4, lo = L & 15;
    // LN1 over all 32 ext rows
    for (int r = wv; r < 32; r += 4) {
        float x0 = (float)out0_s[r][2*L], x1 = (float)out0_s[r][2*L+1];
        float s  = wred(x0 + x1);
        float q  = wred(x0*x0 + x1*x1);
        float mu = s * (1.f/128.f);
        float inv = rsqrtf(q*(1.f/128.f) - mu*mu + LN_EPS);
        h0s[r][2*L]   = (f16)((x0 - mu)*inv*g1s[2*L]   + b1s[2*L]);
        h0s[r][2*L+1] = (f16)((x1 - mu)*inv*g1s[2*L+1] + b1s[2*L+1]);
    }
    __syncthreads();

    // Wx0 = h0 @ Wg1 : M=32, N=128, K=128. B fragments straight from L2-hot wg1T.
    f32x4 acc[2][2];
#pragma unroll
    for (int mg = 0; mg < 2; ++mg)
#pragma unroll
        for (int nt = 0; nt < 2; ++nt) acc[mg][nt] = f32x4{0.f, 0.f, 0.f, 0.f};

#pragma unroll
    for (int kk = 0; kk < 4; ++kk) {
        f16x8 af[2], bfr[2];
#pragma unroll
        for (int mg = 0; mg < 2; ++mg)
            af[mg] = *(const f16x8*)&h0s[mg*16 + lo][kk*32 + hi*8];
#pragma unroll
        for (int nt = 0; nt < 2; ++nt) {
            int n = wv*32 + nt*16 + lo;
            bfr[nt] = *(const f16x8*)(wg1T + n*GH + kk*32 + hi*8);
        }
#pragma unroll
        for (int mg = 0; mg < 2; ++mg)
#pragma unroll
            for (int nt = 0; nt < 2; ++nt)
                acc[mg][nt] = __builtin_amdgcn_mfma_f32_16x16x32_f16(af[mg], bfr[nt], acc[mg][nt], 0, 0, 0);
    }
#pragma unroll
    for (int mg = 0; mg < 2; ++mg)
#pragma unroll
        for (int nt = 0; nt < 2; ++nt)
#pragma unroll
            for (int r = 0; r < 4; ++r)
                wx0_s[mg*16 + hi*4 + r][wv*32 + nt*16 + lo] = (f16)acc[mg][nt][r];
    __syncthreads();

    // out1 rows 1..30 in place: out1[r] = out0[r] + cls[r]*Wx0[r-1] + chs[r]*Wx0[r+1]
    for (int i = tid; i < 30*GH; i += 256) {
        int r = 1 + (i >> 7), g = i & 127;
        float val = (float)out0_s[r][g]
                  + cls[r]*(float)wx0_s[r-1][g]
                  + chs[r]*(float)wx0_s[r+1][g];
        out0_s[r][g] = (f16)val;
    }
    __syncthreads();

    // LN2 + dots for rows 1..30
    for (int r = 1 + wv; r <= 30; r += 4) {
        float x0 = (float)out0_s[r][2*L], x1 = (float)out0_s[r][2*L+1];
        float s  = wred(x0 + x1);
        float q  = wred(x0*x0 + x1*x1);
        float mu = s * (1.f/128.f);
        float inv = rsqrtf(q*(1.f/128.f) - mu*mu + LN_EPS);
        float h0 = (x0 - mu)*inv*g2s[2*L]   + b2s[2*L];
        float h1 = (x1 - mu)*inv*g2s[2*L+1] + b2s[2*L+1];
        float sp = wred(h0*v2s[2*L] + h1*v2s[2*L+1]);   // LN2(out1) . v2
        float yp = wred(x0*wos[2*L] + x1*wos[2*L+1]);   // out1 . Wout
        if (L == 0) { ss[r] = sp; yrs[r] = yp; }
    }
    __syncthreads();

    if (tid < C3) {
        int n = n0 + tid;
        if (n < NN) {
            int r = tid + 2;
            y[(size_t)b*NN + n] = yrs[r] + bout[0] + cls[r]*ss[r-1] + chs[r]*ss[r+1];
        }
    }
}

// ---------------- launcher ----------------
extern "C" void kernel_launch(void* const* d_in, const int* in_sizes, int n_in,
                              void* d_out, int out_size, void* d_ws, size_t ws_size,
                              hipStream_t stream)
{
    (void)in_sizes; (void)n_in; (void)out_size; (void)ws_size;
    const float* x    = (const float*)d_in[0];
    const float* A_hat= (const float*)d_in[1];
    const float* W1   = (const float*)d_in[2];
    const float* b1   = (const float*)d_in[3];
    const float* W2   = (const float*)d_in[4];
    const float* b2   = (const float*)d_in[5];
    const float* Wg1  = (const float*)d_in[6];
    const float* Wg2  = (const float*)d_in[7];
    const float* g1   = (const float*)d_in[8];
    const float* lb1  = (const float*)d_in[9];
    const float* g2   = (const float*)d_in[10];
    const float* lb2  = (const float*)d_in[11];
    const float* Wout = (const float*)d_in[12];
    const float* bout = (const float*)d_in[13];
    float* y = (float*)d_out;

    // ws: [0,32K) h1 f16 | [32K,64K) Wg1^T f16 | [64K,+512) v2 | [80K,+8K) clo |
    //     [88K,+8K) chi | [1M, 1M+32M) out0 f16
    char* ws = (char*)d_ws;
    f16*   h1h  = (f16*)(ws + 0);
    f16*   wg1T = (f16*)(ws + 32768);
    float* v2   = (float*)(ws + 65536);
    float* clo  = (float*)(ws + 81920);
    float* chi  = (float*)(ws + 90112);
    f16*   out0 = (f16*)(ws + (1u << 20));

    k_prep<<<dim3(74),                   256, 0, stream>>>(x, W1, b1, Wg1, Wg2, Wout, A_hat,
                                                           h1h, wg1T, v2, clo, chi);
    k_enc <<<dim3(NG/128),               256, 0, stream>>>(W2, b2, h1h, out0);
    k_gcn <<<dim3((NN + C3 - 1)/C3, B_), 256, 0, stream>>>(clo, chi, g1, lb1, g2, lb2,
                                                           Wout, bout, v2, wg1T, out0, y);
}

// Round 4
// 485.217 us; speedup vs baseline: 1.1068x; 1.0019x over previous
//
#include <hip/hip_runtime.h>

// ChainGNN: B=64, ENC_IN=64, ENC_HID=256, N=2048, GH=128
// Exploits: (1) A_hat tridiagonal (chain) -> neighbor mix, not dense matmul
//           (2) layer-2 collapse: y = out1@Wout + A*(LN(out1)@(Wg2@Wout)) + bout
//           (3) f16 MFMA for encoder GEMM (268MB W2 read is the HBM floor) and layer-1 GEMM
// R4: k_enc 256-col blocks -> 1KB contiguous per W2 row per DMA instr (2x DRAM page
//     efficiency vs 512B). LDS 2-row groups + 16B pad: conflict-free fragment reads.

#define B_    64
#define EIN   64
#define EHID  256
#define NN    2048
#define GH    128
#define NG    (NN*GH)          // 262144
#define LN_EPS 1e-5f
#define C3    28               // nodes per k_gcn block (ext rows = 32 = 2 MFMA m-groups)

typedef _Float16 f16;
typedef _Float16 f16x8 __attribute__((ext_vector_type(8)));
typedef _Float16 f16x4 __attribute__((ext_vector_type(4)));
typedef float    f32x4 __attribute__((ext_vector_type(4)));
typedef unsigned int u32;

#define AS1 __attribute__((address_space(1)))
#define AS3 __attribute__((address_space(3)))

__device__ __forceinline__ float wred(float v) {
#pragma unroll
    for (int off = 32; off > 0; off >>= 1) v += __shfl_xor(v, off, 64);
    return v;
}

// ---- K1: h1=relu(x@W1+b1) f16 | Wg1^T f16 | v2=Wg2@Wout | clo/chi off-diagonals ----
__global__ __launch_bounds__(256) void k_prep(
    const float* __restrict__ x,  const float* __restrict__ W1, const float* __restrict__ b1,
    const float* __restrict__ Wg1,const float* __restrict__ Wg2,const float* __restrict__ Wout,
    const float* __restrict__ A_hat,
    f16* __restrict__ h1h, f16* __restrict__ wg1T, float* __restrict__ v2,
    float* __restrict__ clo, float* __restrict__ chi)
{
    int bid = blockIdx.x, tid = threadIdx.x;
    if (bid < 64) {
        int b = bid, j = tid;
        float acc = b1[j];
#pragma unroll 8
        for (int k = 0; k < EIN; ++k) acc = fmaf(x[b*EIN + k], W1[k*EHID + j], acc);
        h1h[b*EHID + j] = (f16)fmaxf(acc, 0.f);
    } else if (bid == 64) {
        if (tid < GH) {
            float s = 0.f;
            for (int j = 0; j < GH; ++j) s = fmaf(Wg2[tid*GH + j], Wout[j], s);
            v2[tid] = s;
        }
    } else if (bid == 65) {
        for (int i = tid; i < GH*GH; i += 256) {
            int n = i >> 7, k = i & 127;          // wg1T[n][k] = Wg1[k][n]
            wg1T[i] = (f16)Wg1[k*GH + n];
        }
    } else {
        int n = (bid - 66) * 256 + tid;           // bids 66..73 cover n = 0..2047
        clo[n] = (n >= 1)    ? A_hat[(size_t)n*NN + (n-1)] : 0.f;
        chi[n] = (n <= NN-2) ? A_hat[(size_t)n*NN + (n+1)] : 0.f;
    }
}

// ---- K2: out0 = h1 @ W2 + b2  (M=64,K=256,N=262144), f16 out ----
// 256 cols/block. W2 staged 32x256 fp32 double-buffered via global_load_lds dwordx4:
// one wave reads one FULL row (1KB contiguous) per instr -> DRAM-page friendly.
// LDS layout: 2-row groups (2x256 floats) + 4-float pad: group stride 516 floats
// (2064B, 16B-aligned); fragment reads land 2 lanes/bank (free).
__global__ __launch_bounds__(256) void k_enc(
    const float* __restrict__ W2, const float* __restrict__ b2,
    const f16* __restrict__ h1h, f16* __restrict__ out0)
{
    __shared__ float w2s[2][16*516];      // 2 x 33024 B

    int tid = threadIdx.x;
    int L = tid & 63, wv = tid >> 6, hi = L >> 4, lo = L & 15;
    int c0 = blockIdx.x * 256;

    auto stage = [&](int kk, int nb) {
#pragma unroll
        for (int s = 0; s < 8; ++s) {
            int r = wv*8 + s;
            const float* gp = W2 + (size_t)(kk*32 + r) * NG + c0 + L*4;
            float* ldst = &w2s[nb][(r >> 1)*516 + (r & 1)*256];
            __builtin_amdgcn_global_load_lds((const AS1 void*)gp, (AS3 void*)ldst, 16, 0, 0);
        }
    };

    stage(0, 0);

    f32x4 acc[4][4];
#pragma unroll
    for (int bg = 0; bg < 4; ++bg)
#pragma unroll
        for (int t = 0; t < 4; ++t) acc[bg][t] = f32x4{0.f, 0.f, 0.f, 0.f};

#pragma unroll
    for (int kk = 0; kk < 8; ++kk) {
        __syncthreads();                       // drains vmcnt: tile kk resident
        if (kk < 7) stage(kk + 1, (kk + 1) & 1);

        const float* wb = w2s[kk & 1];
        f16x8 bf[4];
#pragma unroll
        for (int t = 0; t < 4; ++t)
#pragma unroll
            for (int j = 0; j < 8; ++j) {
                int row = hi*8 + j;
                bf[t][j] = (f16)wb[(row >> 1)*516 + (row & 1)*256 + wv*64 + t*16 + lo];
            }

        f16x8 af[4];
#pragma unroll
        for (int bg = 0; bg < 4; ++bg)
            af[bg] = *(const f16x8*)(h1h + ((bg*16 + lo) << 8) + kk*32 + hi*8);

#pragma unroll
        for (int bg = 0; bg < 4; ++bg)
#pragma unroll
            for (int t = 0; t < 4; ++t)
                acc[bg][t] = __builtin_amdgcn_mfma_f32_16x16x32_f16(af[bg], bf[t], acc[bg][t], 0, 0, 0);
    }

    float bv[4];
#pragma unroll
    for (int t = 0; t < 4; ++t) bv[t] = b2[c0 + wv*64 + t*16 + lo];
#pragma unroll
    for (int bg = 0; bg < 4; ++bg)
#pragma unroll
        for (int t = 0; t < 4; ++t)
#pragma unroll
            for (int r = 0; r < 4; ++r) {
                int brow = bg*16 + hi*4 + r;      // C/D: row=(lane>>4)*4+reg, col=lane&15
                out0[(size_t)brow * NG + c0 + wv*64 + t*16 + lo] = (f16)(acc[bg][t][r] + bv[t]);
            }
}

// ---- K3 (fused GCN1+GCN2): per (b, 28-node chunk) ->
//   Wx0 = LN1(out0)@Wg1 (ext 32 rows), out1 = out0 + mix(Wx0) (rows 1..30, in LDS),
//   s2 = LN2(out1).v2, yr = out1.Wout, y = yr + bout + mix(s2).
__global__ __launch_bounds__(256) void k_gcn(
    const float* __restrict__ clo, const float* __restrict__ chi,
    const float* __restrict__ ln_g1, const float* __restrict__ ln_b1,
    const float* __restrict__ ln_g2, const float* __restrict__ ln_b2,
    const float* __restrict__ Wout, const float* __restrict__ bout,
    const float* __restrict__ v2, const f16* __restrict__ wg1T,
    const f16* __restrict__ out0, float* __restrict__ y)
{
    __shared__ f16 out0_s[32][132];      // ext rows: nodes n0-2 .. n0+29 (becomes out1 in place)
    __shared__ f16 h0s[32][136];
    __shared__ f16 wx0_s[32][132];
    __shared__ float g1s[GH], b1s[GH], g2s[GH], b2s[GH], v2s[GH], wos[GH];
    __shared__ float cls[32], chs[32];
    __shared__ float ss[32], yrs[32];

    int tid = threadIdx.x;
    int n0 = blockIdx.x * C3;
    int b  = blockIdx.y;

    for (int i = tid; i < 32*32; i += 256) {
        int r = i >> 5, gv = i & 31;
        int n = n0 - 2 + r;
        f16x4 v = {0, 0, 0, 0};
        if (n >= 0 && n < NN) v = *(const f16x4*)(out0 + ((size_t)b*NN + n)*GH + gv*4);
        *(f16x4*)&out0_s[r][gv*4] = v;
    }
    if (tid < GH) {
        g1s[tid] = ln_g1[tid]; b1s[tid] = ln_b1[tid];
        g2s[tid] = ln_g2[tid]; b2s[tid] = ln_b2[tid];
        v2s[tid] = v2[tid];    wos[tid] = Wout[tid];
    } else if (tid < GH + 32) {
        int r = tid - GH, n = n0 - 2 + r;
        bool ok = (n >= 0 && n < NN);
        cls[r] = ok ? clo[n] : 0.f;
        chs[r] = ok ? chi[n] : 0.f;
    }
    __syncthreads();

    int L = tid & 63, wv = tid >> 6, hi = L >> 4, lo = L & 15;
    // LN1 over all 32 ext rows
    for (int r = wv; r < 32; r += 4) {
        float x0 = (float)out0_s[r][2*L], x1 = (float)out0_s[r][2*L+1];
        float s  = wred(x0 + x1);
        float q  = wred(x0*x0 + x1*x1);
        float mu = s * (1.f/128.f);
        float inv = rsqrtf(q*(1.f/128.f) - mu*mu + LN_EPS);
        h0s[r][2*L]   = (f16)((x0 - mu)*inv*g1s[2*L]   + b1s[2*L]);
        h0s[r][2*L+1] = (f16)((x1 - mu)*inv*g1s[2*L+1] + b1s[2*L+1]);
    }
    __syncthreads();

    // Wx0 = h0 @ Wg1 : M=32, N=128, K=128. B fragments straight from L2-hot wg1T.
    f32x4 acc[2][2];
#pragma unroll
    for (int mg = 0; mg < 2; ++mg)
#pragma unroll
        for (int nt = 0; nt < 2; ++nt) acc[mg][nt] = f32x4{0.f, 0.f, 0.f, 0.f};

#pragma unroll
    for (int kk = 0; kk < 4; ++kk) {
        f16x8 af[2], bfr[2];
#pragma unroll
        for (int mg = 0; mg < 2; ++mg)
            af[mg] = *(const f16x8*)&h0s[mg*16 + lo][kk*32 + hi*8];
#pragma unroll
        for (int nt = 0; nt < 2; ++nt) {
            int n = wv*32 + nt*16 + lo;
            bfr[nt] = *(const f16x8*)(wg1T + n*GH + kk*32 + hi*8);
        }
#pragma unroll
        for (int mg = 0; mg < 2; ++mg)
#pragma unroll
            for (int nt = 0; nt < 2; ++nt)
                acc[mg][nt] = __builtin_amdgcn_mfma_f32_16x16x32_f16(af[mg], bfr[nt], acc[mg][nt], 0, 0, 0);
    }
#pragma unroll
    for (int mg = 0; mg < 2; ++mg)
#pragma unroll
        for (int nt = 0; nt < 2; ++nt)
#pragma unroll
            for (int r = 0; r < 4; ++r)
                wx0_s[mg*16 + hi*4 + r][wv*32 + nt*16 + lo] = (f16)acc[mg][nt][r];
    __syncthreads();

    // out1 rows 1..30 in place: out1[r] = out0[r] + cls[r]*Wx0[r-1] + chs[r]*Wx0[r+1]
    for (int i = tid; i < 30*GH; i += 256) {
        int r = 1 + (i >> 7), g = i & 127;
        float val = (float)out0_s[r][g]
                  + cls[r]*(float)wx0_s[r-1][g]
                  + chs[r]*(float)wx0_s[r+1][g];
        out0_s[r][g] = (f16)val;
    }
    __syncthreads();

    // LN2 + dots for rows 1..30
    for (int r = 1 + wv; r <= 30; r += 4) {
        float x0 = (float)out0_s[r][2*L], x1 = (float)out0_s[r][2*L+1];
        float s  = wred(x0 + x1);
        float q  = wred(x0*x0 + x1*x1);
        float mu = s * (1.f/128.f);
        float inv = rsqrtf(q*(1.f/128.f) - mu*mu + LN_EPS);
        float h0 = (x0 - mu)*inv*g2s[2*L]   + b2s[2*L];
        float h1 = (x1 - mu)*inv*g2s[2*L+1] + b2s[2*L+1];
        float sp = wred(h0*v2s[2*L] + h1*v2s[2*L+1]);   // LN2(out1) . v2
        float yp = wred(x0*wos[2*L] + x1*wos[2*L+1]);   // out1 . Wout
        if (L == 0) { ss[r] = sp; yrs[r] = yp; }
    }
    __syncthreads();

    if (tid < C3) {
        int n = n0 + tid;
        if (n < NN) {
            int r = tid + 2;
            y[(size_t)b*NN + n] = yrs[r] + bout[0] + cls[r]*ss[r-1] + chs[r]*ss[r+1];
        }
    }
}

// ---------------- launcher ----------------
extern "C" void kernel_launch(void* const* d_in, const int* in_sizes, int n_in,
                              void* d_out, int out_size, void* d_ws, size_t ws_size,
                              hipStream_t stream)
{
    (void)in_sizes; (void)n_in; (void)out_size; (void)ws_size;
    const float* x    = (const float*)d_in[0];
    const float* A_hat= (const float*)d_in[1];
    const float* W1   = (const float*)d_in[2];
    const float* b1   = (const float*)d_in[3];
    const float* W2   = (const float*)d_in[4];
    const float* b2   = (const float*)d_in[5];
    const float* Wg1  = (const float*)d_in[6];
    const float* Wg2  = (const float*)d_in[7];
    const float* g1   = (const float*)d_in[8];
    const float* lb1  = (const float*)d_in[9];
    const float* g2   = (const float*)d_in[10];
    const float* lb2  = (const float*)d_in[11];
    const float* Wout = (const float*)d_in[12];
    const float* bout = (const float*)d_in[13];
    float* y = (float*)d_out;

    // ws: [0,32K) h1 f16 | [32K,64K) Wg1^T f16 | [64K,+512) v2 | [80K,+8K) clo |
    //     [88K,+8K) chi | [1M, 1M+32M) out0 f16
    char* ws = (char*)d_ws;
    f16*   h1h  = (f16*)(ws + 0);
    f16*   wg1T = (f16*)(ws + 32768);
    float* v2   = (float*)(ws + 65536);
    float* clo  = (float*)(ws + 81920);
    float* chi  = (float*)(ws + 90112);
    f16*   out0 = (f16*)(ws + (1u << 20));

    k_prep<<<dim3(74),                   256, 0, stream>>>(x, W1, b1, Wg1, Wg2, Wout, A_hat,
                                                           h1h, wg1T, v2, clo, chi);
    k_enc <<<dim3(NG/256),               256, 0, stream>>>(W2, b2, h1h, out0);
    k_gcn <<<dim3((NN + C3 - 1)/C3, B_), 256, 0, stream>>>(clo, chi, g1, lb1, g2, lb2,
                                                           Wout, bout, v2, wg1T, out0, y);
}